// Round 1
// baseline (1309.941 us; speedup 1.0000x reference)
//
#include <hip/hip_runtime.h>

#define V      32000
#define V4     8000     // V / 4
#define BLOCK  256

__global__ __launch_bounds__(BLOCK)
void wce_kernel(const float* __restrict__ x,
                const int*   __restrict__ y,
                const float* __restrict__ w,
                float*       __restrict__ out)
{
    const int row = blockIdx.x;
    const float4* __restrict__ xr = (const float4*)(x + (size_t)row * V);
    const float4* __restrict__ w4 = (const float4*)w;

    float s = 0.0f;
    for (int j = threadIdx.x; j < V4; j += BLOCK) {
        float4 xv = xr[j];
        float4 wv = w4[j];
        s += wv.x * __expf(xv.x);
        s += wv.y * __expf(xv.y);
        s += wv.z * __expf(xv.z);
        s += wv.w * __expf(xv.w);
    }

    // wave-64 shuffle reduction
    #pragma unroll
    for (int off = 32; off > 0; off >>= 1)
        s += __shfl_down(s, off, 64);

    __shared__ float ls[BLOCK / 64];
    const int lane = threadIdx.x & 63;
    const int wid  = threadIdx.x >> 6;
    if (lane == 0) ls[wid] = s;
    __syncthreads();

    if (threadIdx.x == 0) {
        float tot = ls[0] + ls[1] + ls[2] + ls[3];
        const int yi = y[row];
        const float gathered = x[(size_t)row * V + yi];
        const float per = w[yi] * (__logf(tot) - gathered);
        atomicAdd(out, per);
    }
}

extern "C" void kernel_launch(void* const* d_in, const int* in_sizes, int n_in,
                              void* d_out, int out_size, void* d_ws, size_t ws_size,
                              hipStream_t stream)
{
    const float* x = (const float*)d_in[0];
    const int*   y = (const int*)d_in[1];
    const float* w = (const float*)d_in[2];
    float* out = (float*)d_out;

    const int B = in_sizes[1];  // 8192 rows

    hipMemsetAsync(d_out, 0, out_size * sizeof(float), stream);
    wce_kernel<<<B, BLOCK, 0, stream>>>(x, y, w, out);
}